// Round 13
// baseline (187.011 us; speedup 1.0000x reference)
//
#include <hip/hip_runtime.h>

#define BATCH 65536

typedef __attribute__((ext_vector_type(8))) short bf16x8;
typedef __attribute__((ext_vector_type(4))) float f32x4;

__device__ __forceinline__ unsigned short f2bf(float f) {
  unsigned int u = __float_as_uint(f);
  u += 0x7fffu + ((u >> 16) & 1u);   // RNE (one-time weight builds only)
  return (unsigned short)(u >> 16);
}
// trunc-pack 2 floats -> 1 dword of 2 bf16 (lo in low half), single v_perm_b32
__device__ __forceinline__ unsigned pack_trunc(float lo, float hi) {
  return __builtin_amdgcn_perm(__float_as_uint(hi), __float_as_uint(lo), 0x07060302u);
}

// tanh(o)*sigmoid(u): 2 exp + 1 rcp; lower-bound clamps keep it NaN-proof.
__device__ __forceinline__ float gru_act(float u, float o) {
  u = fmaxf(u, -60.0f);
  o = fmaxf(o, -30.0f);
  float a  = __expf(-u);
  float a2 = __expf(-2.0f * o);
  return (1.0f - a2) * __builtin_amdgcn_rcpf((1.0f + a) * (1.0f + a2));
}

// conv 3x3 SAME on 3x3 grid, unrolled tap value
__device__ __forceinline__ float conv_tap(const float* __restrict__ w, int co, int ci,
                                          int p, int q, int CINTOT) {
  int pi = p / 3, pj = p % 3, qi = q / 3, qj = q % 3;
  int di = qi - pi + 1, dj = qj - pj + 1;
  if ((unsigned)di < 3u && (unsigned)dj < 3u)
    return w[((co * CINTOT + ci) * 3 + di) * 3 + dj];
  return 0.0f;
}

// BT[g][n][k] bf16, n = co*9+p, k = ci*9+q
__global__ void build_bt(const float* __restrict__ wu, const float* __restrict__ wo,
                         unsigned short* __restrict__ BT, int COUT, int CINX, int CINTOT) {
  int NG = COUT * 9, K = CINX * 9;
  int total = 2 * NG * K;
  int e = blockIdx.x * 256 + threadIdx.x;
  if (e >= total) return;
  int g = e / (NG * K);
  int rem = e - g * (NG * K);
  int n = rem / K, k = rem - n * K;
  BT[e] = f2bf(conv_tap(g ? wo : wu, n / 9, k / 9, n % 9, k % 9, CINTOT));
}

// BT1[g][n][k32] bf16: layer-1 weights, K padded 9->32 with zeros
__global__ void build_bt1(const float* __restrict__ wu, const float* __restrict__ wo,
                          unsigned short* __restrict__ BT1) {
  int e = blockIdx.x * 256 + threadIdx.x;
  if (e >= 18432) return;
  int g = e / 9216;
  int rem = e - g * 9216;
  int n = rem / 32, k = rem - n * 32;
  float v = (k < 9) ? conv_tap(g ? wo : wu, n / 9, 0, n % 9, k, 33) : 0.0f;
  BT1[e] = f2bf(v);
}

// ---------------- LDS layout (bytes), lifetimes barrier-separated ----------------
// [0,40960)     x1l (L1-GEMM epi .. L2 reads) | x3l [0,18688) (L3 epi .. dense)
// [20480,25664) wl (post-L2 .. dense)  [25664,25700) blb  (disjoint from x3l)
// [40960,59392) Bl 288 rows x 64B (L1 GEMM staging only)
// [59392,68608) xl2 64 x 36 f32 (L1 only)
#define OFF_X1L 0
#define OFF_X3L 0
#define OFF_WL 20480
#define OFF_BLB 25664
#define OFF_BL 40960
#define OFF_XL2 59392
#define SMEM_BYTES 68608

// One L2 K-step: MFMA on CUR B-frags, prefetch next step's B into NXT (global->reg).
#define L2_STEP(CUR, NXT, LAST) do {                                        \
    if (!(LAST)) {                                                          \
      _Pragma("unroll") for (int g_ = 0; g_ < 2; ++g_)                      \
        _Pragma("unroll") for (int f_ = 0; f_ < 3; ++f_)                    \
          NXT[g_][f_] = *(const bf16x8*)(BT2 + ldoff + boff[g_][f_]);       \
      if (ktn == 8) { ktn = 0; ldoff += 55040u; }                           \
      else { ++ktn; ldoff += 32u; }                                         \
    }                                                                       \
    bf16x8 af_[4];                                                          \
    const int c8_ = kt * 4 + jc;                                            \
    _Pragma("unroll") for (int m_ = 0; m_ < 4; ++m_)                        \
      af_[m_] = *(const bf16x8*)(aBase[m_] + ((c8_ ^ aXor[m_]) << 4));      \
    _Pragma("unroll") for (int m_ = 0; m_ < 4; ++m_)                        \
      _Pragma("unroll") for (int g_ = 0; g_ < 2; ++g_)                      \
        _Pragma("unroll") for (int f_ = 0; f_ < 3; ++f_)                    \
          acc[m_][g_][f_] = __builtin_amdgcn_mfma_f32_16x16x32_bf16(        \
              af_[m_], CUR[g_][f_], acc[m_][g_][f_], 0, 0, 0);              \
    if (kt == 8) {                                                          \
      _Pragma("unroll") for (int m_ = 0; m_ < 4; ++m_)                      \
        _Pragma("unroll") for (int f_ = 0; f_ < 3; ++f_) {                  \
          int n_ = n0 + (wid * 3 + f_) * 16 + lrow;                         \
          float bU_ = b2u[n_ / 9], bO_ = b2o[n_ / 9];                       \
          f32x4 uv_ = acc[m_][0][f_], ov_ = acc[m_][1][f_];                 \
          _Pragma("unroll") for (int t_ = 0; t_ < 4; ++t_) {                \
            int r_ = r0 + m_ * 16 + jc * 4 + t_;                            \
            x2[(size_t)r_ * 576 + n_] = gru_act(uv_[t_] + bU_, ov_[t_] + bO_); \
          }                                                                 \
          acc[m_][0][f_] = (f32x4){0.f, 0.f, 0.f, 0.f};                     \
          acc[m_][1][f_] = (f32x4){0.f, 0.f, 0.f, 0.f};                     \
        }                                                                   \
      kt = 0; n0 += 192;                                                    \
    } else ++kt;                                                            \
  } while (0)

// One L3 K-step: pack A regs -> af, prefetch next A+B, MFMA.
#define L3_STEP(CURB, NXTB, LAST) do {                                      \
    bf16x8 af_[4];                                                          \
    _Pragma("unroll") for (int m_ = 0; m_ < 4; ++m_) {                      \
      union { uint4 u; bf16x8 v; } cv_;                                     \
      cv_.u.x = pack_trunc(pa0[m_].x, pa0[m_].y);                           \
      cv_.u.y = pack_trunc(pa0[m_].z, pa0[m_].w);                           \
      cv_.u.z = pack_trunc(pa1[m_].x, pa1[m_].y);                           \
      cv_.u.w = pack_trunc(pa1[m_].z, pa1[m_].w);                           \
      af_[m_] = cv_.v;                                                      \
    }                                                                       \
    if (!(LAST)) {                                                          \
      _Pragma("unroll") for (int m_ = 0; m_ < 4; ++m_) {                    \
        pa0[m_] = *(const float4*)(x2r[m_] + a3off);                        \
        pa1[m_] = *(const float4*)(x2r[m_] + a3off + 4);                    \
      }                                                                     \
      a3off += 32u;                                                         \
      _Pragma("unroll") for (int g_ = 0; g_ < 2; ++g_)                      \
        _Pragma("unroll") for (int f_ = 0; f_ < 3; ++f_)                    \
          NXTB[g_][f_] = *(const bf16x8*)(BT3 + b3ld + b3off[g_][f_]);      \
      b3ld += 32u;                                                          \
    }                                                                       \
    _Pragma("unroll") for (int m_ = 0; m_ < 4; ++m_)                        \
      _Pragma("unroll") for (int g_ = 0; g_ < 2; ++g_)                      \
        _Pragma("unroll") for (int f_ = 0; f_ < 3; ++f_)                    \
          acc[m_][g_][f_] = __builtin_amdgcn_mfma_f32_16x16x32_bf16(        \
              af_[m_], CURB[g_][f_], acc[m_][g_][f_], 0, 0, 0);             \
  } while (0)

__global__ __launch_bounds__(256, 2) void megafused(
    const float* __restrict__ xin, const unsigned short* __restrict__ BT1,
    const float* __restrict__ b1u, const float* __restrict__ b1o,
    const unsigned short* __restrict__ BT2,
    const float* __restrict__ b2u, const float* __restrict__ b2o,
    const unsigned short* __restrict__ BT3,
    const float* __restrict__ b3u, const float* __restrict__ b3o,
    const float* __restrict__ wd, const float* __restrict__ bd,
    float* __restrict__ x1, float* __restrict__ x2,
    float* __restrict__ x3, float* __restrict__ out) {
  __shared__ __align__(16) char smem[SMEM_BYTES];
  char* x1l = smem + OFF_X1L;
  char* Bl = smem + OFF_BL;
  unsigned short* x3l = (unsigned short*)(smem + OFF_X3L);
  float* xl2 = (float*)(smem + OFF_XL2);
  float* wl = (float*)(smem + OFF_WL);
  float* blb = (float*)(smem + OFF_BLB);

  const int tid = threadIdx.x;
  const int lane = tid & 63;
  const int wid = tid >> 6;
  const int lrow = lane & 15;
  const int jc = lane >> 4;
  const int r0 = blockIdx.x * 64;

  // per-wave direct B-frag offsets (shorts) into BT2: gate stride 165888
  unsigned boff[2][3];
#pragma unroll
  for (int g = 0; g < 2; ++g)
#pragma unroll
    for (int f = 0; f < 3; ++f)
      boff[g][f] = (unsigned)g * 165888u +
                   (unsigned)(((wid * 3 + f) * 16 + lrow) * 288) + jc * 8;

  // L1 staging constants (288 rows x 4 parts = 1152 chunks, guarded)
  unsigned toffB1[5];
  int wOffG[5];
#pragma unroll
  for (int j = 0; j < 5; ++j) {
    int c = j * 256 + tid;
    if (c < 1152) {
      int row = c >> 2, p = c & 3;
      int g = row >= 144, nloc = row - (g ? 144 : 0);
      toffB1[j] = (unsigned)(g * 288 + nloc) * 32u + p * 8;
      wOffG[j] = row * 64 + ((p ^ ((row >> 1) & 3)) << 4);
    } else {
      toffB1[j] = 0; wOffG[j] = 0;
    }
  }

  // stage x input into zero-padded xl2[64][36]
  for (int c = tid; c < 2304; c += 256) {
    int row = c / 36, col = c - row * 36;
    xl2[c] = (col < 9) ? xin[(size_t)(r0 + row) * 9 + col] : 0.0f;
  }
  bf16x8 pb[5];
#pragma unroll
  for (int j = 0; j < 5; ++j)
    if (j * 256 + tid < 1152) pb[j] = *(const bf16x8*)(BT1 + toffB1[j]);
  __syncthreads();   // xl2 visible

  // A-fragments for L1 (invariant across both chunks)
  bf16x8 afx[4];
#pragma unroll
  for (int m = 0; m < 4; ++m) {
    const float* xr = xl2 + (m * 16 + lrow) * 36 + jc * 8;
    float4 a0 = *(const float4*)xr;
    float4 a1 = *(const float4*)(xr + 4);
    union { uint4 u; bf16x8 v; } cv;
    cv.u.x = pack_trunc(a0.x, a0.y);
    cv.u.y = pack_trunc(a0.z, a0.w);
    cv.u.z = pack_trunc(a1.x, a1.y);
    cv.u.w = pack_trunc(a1.z, a1.w);
    afx[m] = cv.v;
  }
  int rBoffG[2][3];
#pragma unroll
  for (int g = 0; g < 2; ++g)
#pragma unroll
    for (int f = 0; f < 3; ++f) {
      int rb = g * 144 + (wid * 3 + f) * 16 + lrow;
      rBoffG[g][f] = rb * 64 + ((jc ^ ((rb >> 1) & 3)) << 4);
    }

  bf16x8 bX[2][3], bY[2][3];
  // ---- L1 as GEMM: 2 n-chunks of 144 cols/gate, K=32 ----
#pragma unroll
  for (int ch = 0; ch < 2; ++ch) {
#pragma unroll
    for (int j = 0; j < 5; ++j)
      if (j * 256 + tid < 1152) *(bf16x8*)(Bl + wOffG[j]) = pb[j];
    if (ch == 0) {
#pragma unroll
      for (int j = 0; j < 5; ++j)
        if (j * 256 + tid < 1152) pb[j] = *(const bf16x8*)(BT1 + 4608u + toffB1[j]);
    } else {
      // preload L2 step-0 B frags (direct, all waves)
#pragma unroll
      for (int g = 0; g < 2; ++g)
#pragma unroll
        for (int f = 0; f < 3; ++f)
          bX[g][f] = *(const bf16x8*)(BT2 + boff[g][f]);
    }
    __syncthreads();   // Bl ready
    if (wid < 3) {
      f32x4 acc[4][2][3] = {};
      bf16x8 bfr[2][3];
#pragma unroll
      for (int g = 0; g < 2; ++g)
#pragma unroll
        for (int f = 0; f < 3; ++f) bfr[g][f] = *(const bf16x8*)(Bl + rBoffG[g][f]);
#pragma unroll
      for (int m = 0; m < 4; ++m)
#pragma unroll
        for (int g = 0; g < 2; ++g)
#pragma unroll
          for (int f = 0; f < 3; ++f)
            acc[m][g][f] = __builtin_amdgcn_mfma_f32_16x16x32_bf16(
                afx[m], bfr[g][f], acc[m][g][f], 0, 0, 0);
#pragma unroll
      for (int m = 0; m < 4; ++m)
#pragma unroll
        for (int f = 0; f < 3; ++f) {
          int n = ch * 144 + (wid * 3 + f) * 16 + lrow;
          float bU = b1u[n / 9], bO = b1o[n / 9];
          f32x4 uv = acc[m][0][f], ov = acc[m][1][f];
#pragma unroll
          for (int t = 0; t < 4; ++t) {
            int r = m * 16 + jc * 4 + t;
            float v = gru_act(uv[t] + bU, ov[t] + bO);
            x1[(size_t)(r0 + r) * 288 + n] = v;
            *(unsigned short*)(x1l + r * 640 + (((n >> 3) ^ (r & 7)) << 4) + (n & 7) * 2) =
                (unsigned short)(__float_as_uint(v) >> 16);
          }
        }
    }
    __syncthreads();   // Bl consumers done; (ch1) x1l fully visible
  }

  // ---- L2: x1l x BT2(global->reg) -> x2. BARRIER-FREE 27 steps ----
  {
    const char* aBase[4];
    int aXor[4];
#pragma unroll
    for (int m = 0; m < 4; ++m) {
      int row = m * 16 + lrow;
      aBase[m] = x1l + row * 640;
      aXor[m] = row & 7;
    }
    f32x4 acc[4][2][3] = {};
    int kt = 0, n0 = 0, ktn = 1;
    unsigned ldoff = 32u;   // shorts offset of step-1 tile
    for (int sp = 0; sp < 13; ++sp) {
      L2_STEP(bX, bY, false);
      L2_STEP(bY, bX, false);
    }
    L2_STEP(bX, bY, true);  // step 26 (kt==8 -> final epilogue)
  }
  __syncthreads();   // x2 stores drained (all waves); x1l dead

  // stage dense weights (regions disjoint from x3l)
  for (int c = tid; c < 1296; c += 256) wl[c] = wd[c];
  if (tid < 9) blb[tid] = bd[tid];

  // ---- L3: x2(global->reg) x BT3(global->reg). BARRIER-FREE 18 steps ----
  if (wid < 3) {
    unsigned b3off[2][3];
#pragma unroll
    for (int g = 0; g < 2; ++g)
#pragma unroll
      for (int f = 0; f < 3; ++f)
        b3off[g][f] = (unsigned)g * 82944u +
                      (unsigned)(((wid * 3 + f) * 16 + lrow) * 576) + jc * 8;
    const float* x2r[4];
#pragma unroll
    for (int m = 0; m < 4; ++m)
      x2r[m] = x2 + (size_t)(r0 + m * 16 + lrow) * 576 + jc * 8;

    // prologue: load kt=0 A and B (covered by wl staging)
    float4 pa0[4], pa1[4];
#pragma unroll
    for (int m = 0; m < 4; ++m) {
      pa0[m] = *(const float4*)(x2r[m]);
      pa1[m] = *(const float4*)(x2r[m] + 4);
    }
    bf16x8 bX3[2][3], bY3[2][3];
#pragma unroll
    for (int g = 0; g < 2; ++g)
#pragma unroll
      for (int f = 0; f < 3; ++f)
        bX3[g][f] = *(const bf16x8*)(BT3 + b3off[g][f]);

    f32x4 acc[4][2][3] = {};
    unsigned a3off = 32u, b3ld = 32u;
    for (int sp = 0; sp < 8; ++sp) {
      L3_STEP(bX3, bY3, false);
      L3_STEP(bY3, bX3, false);
    }
    L3_STEP(bX3, bY3, false);   // step 16
    L3_STEP(bY3, bX3, true);    // step 17

    // epilogue: act -> x3 global fp32 + x3l (LDS bf16, trunc)
#pragma unroll
    for (int m = 0; m < 4; ++m)
#pragma unroll
      for (int f = 0; f < 3; ++f) {
        int n = (wid * 3 + f) * 16 + lrow;
        float bU = b3u[n / 9], bO = b3o[n / 9];
        f32x4 uv = acc[m][0][f], ov = acc[m][1][f];
#pragma unroll
        for (int t = 0; t < 4; ++t) {
          int r = m * 16 + jc * 4 + t;
          float v = gru_act(uv[t] + bU, ov[t] + bO);
          x3[(size_t)(r0 + r) * 144 + n] = v;
          x3l[r * 146 + n] = (unsigned short)(__float_as_uint(v) >> 16);
        }
      }
  }
  __syncthreads();   // x3l + wl ready (wave 3 waits here)

  // ---- dense head: 3 waves, 3 cols each ----
  if (wid < 3) {
    int drow = lane;
    int jb = wid * 3;
    float s0 = blb[jb], s1 = blb[jb + 1], s2 = blb[jb + 2];
    for (int k = 0; k < 144; k += 2) {
      unsigned pr = *(const unsigned*)&x3l[drow * 146 + k];
      float v0 = __uint_as_float(pr << 16);
      float v1 = __uint_as_float(pr & 0xffff0000u);
      const float2 w0 = *(const float2*)&wl[jb * 144 + k];
      const float2 w1 = *(const float2*)&wl[(jb + 1) * 144 + k];
      const float2 w2 = *(const float2*)&wl[(jb + 2) * 144 + k];
      s0 = fmaf(v0, w0.x, s0); s0 = fmaf(v1, w0.y, s0);
      s1 = fmaf(v0, w1.x, s1); s1 = fmaf(v1, w1.y, s1);
      s2 = fmaf(v0, w2.x, s2); s2 = fmaf(v1, w2.y, s2);
    }
    size_t ob = (size_t)(r0 + drow) * 9 + jb;
    out[ob] = s0; out[ob + 1] = s1; out[ob + 2] = s2;
  }
}

extern "C" void kernel_launch(void* const* d_in, const int* in_sizes, int n_in,
                              void* d_out, int out_size, void* d_ws, size_t ws_size,
                              hipStream_t stream) {
  const float* inputs = (const float*)d_in[0];
  const float* wd  = (const float*)d_in[1];
  const float* bd  = (const float*)d_in[2];
  const float* w1u = (const float*)d_in[3];
  const float* b1u = (const float*)d_in[4];
  const float* w1o = (const float*)d_in[7];
  const float* b1o = (const float*)d_in[8];
  const float* w2u = (const float*)d_in[9];
  const float* b2u = (const float*)d_in[10];
  const float* w2o = (const float*)d_in[13];
  const float* b2o = (const float*)d_in[14];
  const float* w3u = (const float*)d_in[15];
  const float* b3u = (const float*)d_in[16];
  const float* w3o = (const float*)d_in[19];
  const float* b3o = (const float*)d_in[20];

  float* out = (float*)d_out;                    // [B][9]
  float* x1 = out + (size_t)BATCH * 9;           // [B][288]
  float* x2 = x1 + (size_t)BATCH * 288;          // [B][576]
  float* x3 = x2 + (size_t)BATCH * 576;          // [B][144]

  unsigned short* BT2 = (unsigned short*)d_ws;   // [2][576][288] bf16
  unsigned short* BT3 = BT2 + 331776;            // [2][144][576] bf16
  unsigned short* BT1 = BT3 + 165888;            // [2][288][32]  bf16

  build_bt<<<1296, 256, 0, stream>>>(w2u, w2o, BT2, 64, 32, 96);
  build_bt<<<648, 256, 0, stream>>>(w3u, w3o, BT3, 16, 64, 80);
  build_bt1<<<72, 256, 0, stream>>>(w1u, w1o, BT1);

  megafused<<<BATCH / 64, 256, 0, stream>>>(inputs, BT1, b1u, b1o, BT2, b2u, b2o,
                                            BT3, b3u, b3o, wd, bd, x1, x2, x3, out);
}